// Round 4
// baseline (55.442 us; speedup 1.0000x reference)
//
#include <hip/hip_runtime.h>

namespace {
constexpr int Bn = 4, Dn = 4, Hn = 768, Wn = 768;
constexpr int HWc = Hn * Wn;                       // 589824
constexpr size_t DHWc = (size_t)Dn * HWc;          // 2359296
constexpr float BONUS = 10.0f;
constexpr int CAP = 384;        // max strict maxima per (b,h) region: <=383 (no two w-adjacent, d in {1,2})
constexpr int NREG = Bn * Hn;   // 3072 regions
}

// ---------------- Kernel A: NMS + trivial outputs + maxima list ----------------
// One thread: 4-wide w window x all 4 d slices. Maxima can only occur at
// d in {1,2}, h in [1,766], w in [1,766] (replicate pad => strict '>' fails on
// boundaries), so NMS runs only on d=1,2 and only for interior-h blocks.
__global__ __launch_bounds__(192) void cqiA(const float* __restrict__ x,
                                            float* __restrict__ coords,
                                            float* __restrict__ ymax,
                                            unsigned* __restrict__ counts,
                                            unsigned* __restrict__ list) {
#pragma clang fp contract(off)
    __shared__ unsigned lctr;
    int id = blockIdx.x;
    id = (id & 7) * (NREG >> 3) + (id >> 3);   // XCD-contiguous swizzle (3072 % 8 == 0)
    const int h = id % Hn;
    const int b = id / Hn;
    const int t = threadIdx.x;
    const int w0 = t << 2;

    const float* base = x + (size_t)b * DHWc;
    float* cb = coords + (size_t)b * 3 * DHWc;
    float* yb = ymax + (size_t)b * DHWc;

    if (t == 0) lctr = 0;
    const bool hinterior = (h > 0) && (h < Hn - 1);
    __syncthreads();

    if (!hinterior) {
        // boundary rows: every voxel trivial (strict NMS impossible)
#pragma unroll
        for (int d = 0; d < 4; ++d) {
            const size_t sp = (size_t)d * HWc + (size_t)h * Wn + (size_t)w0;
            const float4 q = *reinterpret_cast<const float4*>(base + sp);
            *reinterpret_cast<float4*>(cb + sp)            = make_float4((float)d, (float)d, (float)d, (float)d);
            *reinterpret_cast<float4*>(cb + DHWc + sp)     = make_float4((float)w0, (float)(w0+1), (float)(w0+2), (float)(w0+3));
            *reinterpret_cast<float4*>(cb + 2 * DHWc + sp) = make_float4((float)h, (float)h, (float)h, (float)h);
            *reinterpret_cast<float4*>(yb + sp)            = q;
        }
        if (t == 0) counts[id] = 0;
        return;
    }

    const int wl = (w0 == 0) ? 0 : w0 - 1;
    const int wr = (w0 + 4 < Wn) ? w0 + 4 : Wn - 1;
    const int hz[3] = {h - 1, h, h + 1};

    // v[a][dd][c]: a = h-axis, dd = d-slice, c: 0 = w0-1, 1..4 = w0..w0+3, 5 = w0+4
    float v[3][4][6];
#pragma unroll
    for (int a = 0; a < 3; ++a) {
#pragma unroll
        for (int dd = 0; dd < 4; ++dd) {
            const float* ph = base + (size_t)dd * HWc + (size_t)hz[a] * Wn;
            const float4 q = *reinterpret_cast<const float4*>(ph + w0);
            v[a][dd][0] = ph[wl];
            v[a][dd][1] = q.x;
            v[a][dd][2] = q.y;
            v[a][dd][3] = q.z;
            v[a][dd][4] = q.w;
            v[a][dd][5] = ph[wr];
        }
    }

    // trivial outputs for all 16 voxels (maxima overwritten by kernel B)
#pragma unroll
    for (int d = 0; d < 4; ++d) {
        const size_t sp = (size_t)d * HWc + (size_t)h * Wn + (size_t)w0;
        *reinterpret_cast<float4*>(cb + sp)            = make_float4((float)d, (float)d, (float)d, (float)d);
        *reinterpret_cast<float4*>(cb + DHWc + sp)     = make_float4((float)w0, (float)(w0+1), (float)(w0+2), (float)(w0+3));
        *reinterpret_cast<float4*>(cb + 2 * DHWc + sp) = make_float4((float)h, (float)h, (float)h, (float)h);
        *reinterpret_cast<float4*>(yb + sp)            = make_float4(v[1][d][1], v[1][d][2], v[1][d][3], v[1][d][4]);
    }

    // NMS on d = 1, 2 only; fmax chains are exact so ordering is free
#pragma unroll
    for (int d = 1; d <= 2; ++d) {
        const int s0 = d - 1;
        const int s2 = d + 1;
        float colNC[6], cmax[6];
#pragma unroll
        for (int c = 0; c < 6; ++c) {
            float m = v[0][s0][c];
            m = fmaxf(m, v[1][s0][c]);
            m = fmaxf(m, v[2][s0][c]);
            m = fmaxf(m, v[0][d][c]);
            m = fmaxf(m, v[2][d][c]);
            m = fmaxf(m, v[0][s2][c]);
            m = fmaxf(m, v[1][s2][c]);
            m = fmaxf(m, v[2][s2][c]);
            colNC[c] = m;
            cmax[c] = fmaxf(m, v[1][d][c]);
        }
#pragma unroll
        for (int j = 0; j < 4; ++j) {
            const int cc = j + 1;
            const float xc = v[1][d][cc];
            const float m = fmaxf(fmaxf(cmax[cc - 1], cmax[cc + 1]), fmaxf(colNC[cc], 0.0f));
            if (xc > m) {
                const unsigned slot = atomicAdd(&lctr, 1u);
                if (slot < CAP)
                    list[(size_t)id * CAP + slot] = (unsigned)((d << 10) | (w0 + j));
            }
        }
    }

    __syncthreads();
    if (t == 0) counts[id] = (lctr < (unsigned)CAP) ? lctr : (unsigned)CAP;
}

// ---------------- Kernel B: sparse solve at maxima ----------------
__global__ __launch_bounds__(256) void cqiB(const float* __restrict__ x,
                                            float* __restrict__ coords,
                                            float* __restrict__ ymax,
                                            const unsigned* __restrict__ counts,
                                            const unsigned* __restrict__ list) {
#pragma clang fp contract(off)
    const int id = blockIdx.x;
    const int h = id % Hn;
    const int b = id / Hn;
    const unsigned n = counts[id];
    const float* base = x + (size_t)b * DHWc;
    float* cb = coords + (size_t)b * 3 * DHWc;

    for (unsigned jj = threadIdx.x; jj < n; jj += 256) {
        const unsigned e = list[(size_t)id * CAP + jj];
        const int d = (int)(e >> 10);
        const int w = (int)(e & 1023u);

        // q[a][s][c]: a = h-1..h+1, s = d-1..d+1, c = w-1..w+1 (all interior)
        float q[3][3][3];
#pragma unroll
        for (int a = 0; a < 3; ++a)
#pragma unroll
            for (int s = 0; s < 3; ++s) {
                const float* p = base + (size_t)(d - 1 + s) * HWc + (size_t)(h - 1 + a) * Wn + (w - 1);
                q[a][s][0] = p[0];
                q[a][s][1] = p[1];
                q[a][s][2] = p[2];
            }

        const float xc = q[1][1][1];
        const float gx  = 0.5f * (q[1][1][2] - q[1][1][0]);
        const float gy  = 0.5f * (q[2][1][1] - q[0][1][1]);
        const float gs  = 0.5f * (q[1][2][1] - q[1][0][1]);
        const float dxx = q[1][1][2] - 2.0f * xc + q[1][1][0];
        const float dyy = q[2][1][1] - 2.0f * xc + q[0][1][1];
        const float dss = q[1][2][1] - 2.0f * xc + q[1][0][1];
        const float dxy =  0.25f * (q[2][1][2] - q[2][1][0] - q[0][1][2] + q[0][1][0]);
        const float dys = -0.25f * (q[2][2][1] - q[0][2][1] - q[2][0][1] + q[0][0][1]);
        const float dxs = -0.25f * (q[1][2][2] - q[1][2][0] - q[1][0][2] + q[1][0][0]);

        const float cf00 = dyy * dss - dys * dys;
        const float cf01 = dxy * dss - dys * dxs;
        const float cf02 = dxy * dys - dyy * dxs;
        const float det  = dxx * cf00 - dxy * cf01 + dxs * cf02;
        const bool solved = fabsf(det) > 0.0f;   // valid = nms && solved; nms true here
        const float sd = solved ? det : 1.0f;

        const float t0 = gy * dss - dys * gs;
        const float sx = (gx * cf00 - dxy * t0 + dxs * (gy * dys - dyy * gs)) / sd;
        const float sy = (dxx * t0 - gx * cf01 + dxs * (dxy * gs - gy * dxs)) / sd;
        const float ss = (dxx * (dyy * gs - gy * dys) - dxy * (dxy * gs - gy * dxs) + gx * cf02) / sd;

        float dxv = solved ? -sx : 0.0f;
        float dyv = solved ? -sy : 0.0f;
        float dsv = solved ? -ss : 0.0f;
        const float mx = fmaxf(fmaxf(fabsf(dxv), fabsf(dyv)), fabsf(dsv));
        if (mx > 0.7f) { dxv = 0.0f; dyv = 0.0f; dsv = 0.0f; }

        const float dy_ = 0.5f * (gx * dxv + gy * dyv + gs * dsv);
        float y = xc + dy_;
        if (solved) y += BONUS;   // bonus applies even when the offset was rejected

        const size_t sp = (size_t)d * HWc + (size_t)h * Wn + (size_t)w;
        cb[sp]             = (float)d + dsv;
        cb[DHWc + sp]      = (float)w + dxv;
        cb[2 * DHWc + sp]  = (float)h + dyv;
        ymax[(size_t)b * DHWc + sp] = y;
    }
}

// ---------------- Fallback: round-3 monolithic kernel (if ws too small) ----------------
__global__ __launch_bounds__(192) void cqi3d(const float* __restrict__ x,
                                             float* __restrict__ coords,
                                             float* __restrict__ ymax) {
#pragma clang fp contract(off)
    int id = blockIdx.x;
    id = (id & 7) * ((Hn * Bn) >> 3) + (id >> 3);
    const int h = id % Hn;
    const int b = id / Hn;
    const int t = threadIdx.x;
    const int w0 = t << 2;

    const float* base = x + (size_t)b * DHWc;
    const int hm = h > 0 ? h - 1 : 0;
    const int hp = h < Hn - 1 ? h + 1 : Hn - 1;
    const int wl = (w0 == 0) ? 0 : w0 - 1;
    const int wr = (w0 + 4 < Wn) ? w0 + 4 : Wn - 1;
    const int hz[3] = {hm, h, hp};

    float v[3][4][6];
#pragma unroll
    for (int a = 0; a < 3; ++a) {
#pragma unroll
        for (int dd = 0; dd < 4; ++dd) {
            const float* ph = base + (size_t)dd * HWc + (size_t)hz[a] * Wn;
            const float4 q = *reinterpret_cast<const float4*>(ph + w0);
            v[a][dd][0] = ph[wl];
            v[a][dd][1] = q.x;
            v[a][dd][2] = q.y;
            v[a][dd][3] = q.z;
            v[a][dd][4] = q.w;
            v[a][dd][5] = ph[wr];
        }
    }

    float* cb = coords + (size_t)b * 3 * DHWc;

#pragma unroll
    for (int d = 0; d < 4; ++d) {
        const int s0 = d > 0 ? d - 1 : 0;
        const int s2 = d < 3 ? d + 1 : 3;
        float colNC[6], cmax[6];
#pragma unroll
        for (int c = 0; c < 6; ++c) {
            float m = v[0][s0][c];
            m = fmaxf(m, v[1][s0][c]);
            m = fmaxf(m, v[2][s0][c]);
            m = fmaxf(m, v[0][d][c]);
            m = fmaxf(m, v[2][d][c]);
            m = fmaxf(m, v[0][s2][c]);
            m = fmaxf(m, v[1][s2][c]);
            m = fmaxf(m, v[2][s2][c]);
            colNC[c] = m;
            cmax[c] = fmaxf(m, v[1][d][c]);
        }

        float outz[4], outx[4], outy[4], outv[4];
#pragma unroll
        for (int j = 0; j < 4; ++j) {
            const int cc = j + 1;
            const float xc = v[1][d][cc];
            const float m = fmaxf(fmaxf(cmax[cc - 1], cmax[cc + 1]), fmaxf(colNC[cc], 0.0f));
            const bool nms = xc > m;

            const float gx  = 0.5f * (v[1][d][cc + 1] - v[1][d][cc - 1]);
            const float gy  = 0.5f * (v[2][d][cc] - v[0][d][cc]);
            const float gs  = 0.5f * (v[1][s2][cc] - v[1][s0][cc]);
            const float dxx = v[1][d][cc + 1] - 2.0f * xc + v[1][d][cc - 1];
            const float dyy = v[2][d][cc] - 2.0f * xc + v[0][d][cc];
            const float dss = v[1][s2][cc] - 2.0f * xc + v[1][s0][cc];
            const float dxy =  0.25f * (v[2][d][cc + 1] - v[2][d][cc - 1] - v[0][d][cc + 1] + v[0][d][cc - 1]);
            const float dys = -0.25f * (v[2][s2][cc] - v[0][s2][cc] - v[2][s0][cc] + v[0][s0][cc]);
            const float dxs = -0.25f * (v[1][s2][cc + 1] - v[1][s2][cc - 1] - v[1][s0][cc + 1] + v[1][s0][cc - 1]);

            const float cf00 = dyy * dss - dys * dys;
            const float cf01 = dxy * dss - dys * dxs;
            const float cf02 = dxy * dys - dyy * dxs;
            const float det  = dxx * cf00 - dxy * cf01 + dxs * cf02;
            const bool solved = fabsf(det) > 0.0f;
            const float sd = solved ? det : 1.0f;

            const float t0 = gy * dss - dys * gs;
            const float sx = (gx * cf00 - dxy * t0 + dxs * (gy * dys - dyy * gs)) / sd;
            const float sy = (dxx * t0 - gx * cf01 + dxs * (dxy * gs - gy * dxs)) / sd;
            const float ss = (dxx * (dyy * gs - gy * dys) - dxy * (dxy * gs - gy * dxs) + gx * cf02) / sd;

            const bool valid = nms && solved;
            float dxv = valid ? -sx : 0.0f;
            float dyv = valid ? -sy : 0.0f;
            float dsv = valid ? -ss : 0.0f;
            const float mx = fmaxf(fmaxf(fabsf(dxv), fabsf(dyv)), fabsf(dsv));
            if (mx > 0.7f) { dxv = 0.0f; dyv = 0.0f; dsv = 0.0f; }

            const float dy_ = 0.5f * (gx * dxv + gy * dyv + gs * dsv);
            float y = xc + dy_;
            if (valid) y += BONUS;

            outz[j] = (float)d + dsv;
            outx[j] = (float)(w0 + j) + dxv;
            outy[j] = (float)h + dyv;
            outv[j] = y;
        }

        const size_t sp = (size_t)d * HWc + (size_t)h * Wn + (size_t)w0;
        *reinterpret_cast<float4*>(cb + sp)            = make_float4(outz[0], outz[1], outz[2], outz[3]);
        *reinterpret_cast<float4*>(cb + DHWc + sp)     = make_float4(outx[0], outx[1], outx[2], outx[3]);
        *reinterpret_cast<float4*>(cb + 2 * DHWc + sp) = make_float4(outy[0], outy[1], outy[2], outy[3]);
        *reinterpret_cast<float4*>(ymax + (size_t)b * DHWc + sp)
                                                       = make_float4(outv[0], outv[1], outv[2], outv[3]);
    }
}

extern "C" void kernel_launch(void* const* d_in, const int* in_sizes, int n_in,
                              void* d_out, int out_size, void* d_ws, size_t ws_size,
                              hipStream_t stream) {
    const float* x = (const float*)d_in[0];
    float* out = (float*)d_out;
    float* coords = out;                          // (B,1,3,D,H,W) flat
    float* ymaxp  = out + (size_t)Bn * 3 * DHWc;  // (B,1,D,H,W) flat

    const size_t need = (size_t)NREG * 4 + (size_t)NREG * CAP * 4;
    if (d_ws != nullptr && ws_size >= need) {
        unsigned* counts = (unsigned*)d_ws;
        unsigned* lst = counts + NREG;
        cqiA<<<dim3(NREG), dim3(192, 1, 1), 0, stream>>>(x, coords, ymaxp, counts, lst);
        cqiB<<<dim3(NREG), dim3(256, 1, 1), 0, stream>>>(x, coords, ymaxp, counts, lst);
    } else {
        cqi3d<<<dim3(NREG), dim3(192, 1, 1), 0, stream>>>(x, coords, ymaxp);
    }
}

// Round 5
// 34.630 us; speedup vs baseline: 1.6010x; 1.6010x over previous
//
#include <hip/hip_runtime.h>

namespace {
constexpr int Bn = 4, Dn = 4, Hn = 768, Wn = 768;
constexpr int HWc = Hn * Wn;                       // 589824
constexpr size_t DHWc = (size_t)Dn * HWc;          // 2359296
constexpr float BONUS = 10.0f;
}

// Monolithic: one thread = 4-wide w window x all 4 d slices (16 voxels).
// Key structural fact (verified exactly in round 4): replicate-pad + strict '>'
// means NMS maxima can only occur at d in {1,2}, h in [1,766], w in [1,766].
// So the expensive path (NMS + Cramer + 3 IEEE divides) runs only for d=1,2;
// d=0,3 and boundary-h rows emit coords=(d,w,h), y=x directly.
__global__ __launch_bounds__(192) void cqi3d(const float* __restrict__ x,
                                             float* __restrict__ coords,
                                             float* __restrict__ ymax) {
#pragma clang fp contract(off)
    int id = blockIdx.x;
    id = (id & 7) * ((Hn * Bn) >> 3) + (id >> 3);   // XCD-contiguous swizzle
    const int h = id % Hn;
    const int b = id / Hn;
    const int t = threadIdx.x;
    const int w0 = t << 2;

    const float* base = x + (size_t)b * DHWc;
    float* cb = coords + (size_t)b * 3 * DHWc;
    float* yb = ymax + (size_t)b * DHWc;

    const float4 cz0 = make_float4(0.f, 0.f, 0.f, 0.f);
    const float4 cz3 = make_float4(3.f, 3.f, 3.f, 3.f);
    const float4 cx  = make_float4((float)w0, (float)(w0 + 1), (float)(w0 + 2), (float)(w0 + 3));
    const float4 cy  = make_float4((float)h, (float)h, (float)h, (float)h);

    if (h == 0 || h == Hn - 1) {
        // boundary row: every voxel trivial; only center-row loads needed
#pragma unroll
        for (int d = 0; d < 4; ++d) {
            const size_t sp = (size_t)d * HWc + (size_t)h * Wn + (size_t)w0;
            const float4 q = *reinterpret_cast<const float4*>(base + sp);
            *reinterpret_cast<float4*>(cb + sp)            = make_float4((float)d, (float)d, (float)d, (float)d);
            *reinterpret_cast<float4*>(cb + DHWc + sp)     = cx;
            *reinterpret_cast<float4*>(cb + 2 * DHWc + sp) = cy;
            *reinterpret_cast<float4*>(yb + sp)            = q;
        }
        return;
    }

    const int wl = (w0 == 0) ? 0 : w0 - 1;
    const int wr = (w0 + 4 < Wn) ? w0 + 4 : Wn - 1;
    const int hz[3] = {h - 1, h, h + 1};

    // v[a][dd][c]: a = h-axis, dd = d-slice, c: 0 = w0-1, 1..4 = w0..w0+3, 5 = w0+4
    float v[3][4][6];
#pragma unroll
    for (int a = 0; a < 3; ++a) {
#pragma unroll
        for (int dd = 0; dd < 4; ++dd) {
            const float* ph = base + (size_t)dd * HWc + (size_t)hz[a] * Wn;
            const float4 q = *reinterpret_cast<const float4*>(ph + w0);
            v[a][dd][0] = ph[wl];
            v[a][dd][1] = q.x;
            v[a][dd][2] = q.y;
            v[a][dd][3] = q.z;
            v[a][dd][4] = q.w;
            v[a][dd][5] = ph[wr];
        }
    }

    // d = 0 and d = 3: trivial (strict NMS impossible vs replicated self)
    {
        const size_t sp0 = (size_t)h * Wn + (size_t)w0;
        *reinterpret_cast<float4*>(cb + sp0)            = cz0;
        *reinterpret_cast<float4*>(cb + DHWc + sp0)     = cx;
        *reinterpret_cast<float4*>(cb + 2 * DHWc + sp0) = cy;
        *reinterpret_cast<float4*>(yb + sp0)            = make_float4(v[1][0][1], v[1][0][2], v[1][0][3], v[1][0][4]);
        const size_t sp3 = 3 * (size_t)HWc + sp0;
        *reinterpret_cast<float4*>(cb + sp3)            = cz3;
        *reinterpret_cast<float4*>(cb + DHWc + sp3)     = cx;
        *reinterpret_cast<float4*>(cb + 2 * DHWc + sp3) = cy;
        *reinterpret_cast<float4*>(yb + sp3)            = make_float4(v[1][3][1], v[1][3][2], v[1][3][3], v[1][3][4]);
    }

    // d = 1, 2: full NMS + quadratic interpolation
#pragma unroll
    for (int d = 1; d <= 2; ++d) {
        const int s0 = d - 1;
        const int s2 = d + 1;
        float colNC[6], cmax[6];
#pragma unroll
        for (int c = 0; c < 6; ++c) {
            float m = v[0][s0][c];
            m = fmaxf(m, v[1][s0][c]);
            m = fmaxf(m, v[2][s0][c]);
            m = fmaxf(m, v[0][d][c]);
            m = fmaxf(m, v[2][d][c]);
            m = fmaxf(m, v[0][s2][c]);
            m = fmaxf(m, v[1][s2][c]);
            m = fmaxf(m, v[2][s2][c]);
            colNC[c] = m;
            cmax[c] = fmaxf(m, v[1][d][c]);
        }

        float outz[4], outx[4], outy[4], outv[4];
#pragma unroll
        for (int j = 0; j < 4; ++j) {
            const int cc = j + 1;
            const float xc = v[1][d][cc];
            const float m = fmaxf(fmaxf(cmax[cc - 1], cmax[cc + 1]), fmaxf(colNC[cc], 0.0f));
            const bool nms = xc > m;

            const float gx  = 0.5f * (v[1][d][cc + 1] - v[1][d][cc - 1]);
            const float gy  = 0.5f * (v[2][d][cc] - v[0][d][cc]);
            const float gs  = 0.5f * (v[1][s2][cc] - v[1][s0][cc]);
            const float dxx = v[1][d][cc + 1] - 2.0f * xc + v[1][d][cc - 1];
            const float dyy = v[2][d][cc] - 2.0f * xc + v[0][d][cc];
            const float dss = v[1][s2][cc] - 2.0f * xc + v[1][s0][cc];
            const float dxy =  0.25f * (v[2][d][cc + 1] - v[2][d][cc - 1] - v[0][d][cc + 1] + v[0][d][cc - 1]);
            const float dys = -0.25f * (v[2][s2][cc] - v[0][s2][cc] - v[2][s0][cc] + v[0][s0][cc]);
            const float dxs = -0.25f * (v[1][s2][cc + 1] - v[1][s2][cc - 1] - v[1][s0][cc + 1] + v[1][s0][cc - 1]);

            const float cf00 = dyy * dss - dys * dys;
            const float cf01 = dxy * dss - dys * dxs;
            const float cf02 = dxy * dys - dyy * dxs;
            const float det  = dxx * cf00 - dxy * cf01 + dxs * cf02;
            const bool solved = fabsf(det) > 0.0f;
            const float sd = solved ? det : 1.0f;

            const float t0 = gy * dss - dys * gs;
            const float sx = (gx * cf00 - dxy * t0 + dxs * (gy * dys - dyy * gs)) / sd;
            const float sy = (dxx * t0 - gx * cf01 + dxs * (dxy * gs - gy * dxs)) / sd;
            const float ss = (dxx * (dyy * gs - gy * dys) - dxy * (dxy * gs - gy * dxs) + gx * cf02) / sd;

            const bool valid = nms && solved;
            float dxv = valid ? -sx : 0.0f;
            float dyv = valid ? -sy : 0.0f;
            float dsv = valid ? -ss : 0.0f;
            const float mx = fmaxf(fmaxf(fabsf(dxv), fabsf(dyv)), fabsf(dsv));
            if (mx > 0.7f) { dxv = 0.0f; dyv = 0.0f; dsv = 0.0f; }

            const float dy_ = 0.5f * (gx * dxv + gy * dyv + gs * dsv);
            float y = xc + dy_;
            if (valid) y += BONUS;

            outz[j] = (float)d + dsv;
            outx[j] = (float)(w0 + j) + dxv;
            outy[j] = (float)h + dyv;
            outv[j] = y;
        }

        const size_t sp = (size_t)d * HWc + (size_t)h * Wn + (size_t)w0;
        *reinterpret_cast<float4*>(cb + sp)            = make_float4(outz[0], outz[1], outz[2], outz[3]);
        *reinterpret_cast<float4*>(cb + DHWc + sp)     = make_float4(outx[0], outx[1], outx[2], outx[3]);
        *reinterpret_cast<float4*>(cb + 2 * DHWc + sp) = make_float4(outy[0], outy[1], outy[2], outy[3]);
        *reinterpret_cast<float4*>(yb + sp)            = make_float4(outv[0], outv[1], outv[2], outv[3]);
    }
}

extern "C" void kernel_launch(void* const* d_in, const int* in_sizes, int n_in,
                              void* d_out, int out_size, void* d_ws, size_t ws_size,
                              hipStream_t stream) {
    const float* x = (const float*)d_in[0];
    float* out = (float*)d_out;
    float* coords = out;                          // (B,1,3,D,H,W) flat
    float* ymaxp  = out + (size_t)Bn * 3 * DHWc;  // (B,1,D,H,W) flat
    cqi3d<<<dim3(Hn * Bn), dim3(192, 1, 1), 0, stream>>>(x, coords, ymaxp);
}